// Round 7
// baseline (235.509 us; speedup 1.0000x reference)
//
#include <hip/hip_runtime.h>
#include <hip/hip_bf16.h>

#define HH 192
#define WW 192
#define HWPROD (192*192)
#define EPSBN 1e-5f
#define NSTRIP 2304

typedef _Float16 f16x8 __attribute__((ext_vector_type(8)));
typedef _Float16 f16x4 __attribute__((ext_vector_type(4)));
typedef _Float16 f16x2 __attribute__((ext_vector_type(2)));
typedef float f32x4 __attribute__((ext_vector_type(4)));
typedef float f32x16 __attribute__((ext_vector_type(16)));

// ---------------------------------------------------------------------------
// prep_conv0 (R16 version, + zeroes the work-steal counter for the main
// kernel; re-zeroed every launch so graph replay is safe).
//  blocks [0,1152): conv0, coalesced f16x8 stores (R16).
//  blocks [1152,1414): whF/lbf/wnP prep (proven mapping) + cnt=0.
// ---------------------------------------------------------------------------
__global__ __launch_bounds__(256) void prep_conv0_k(
                       const float* __restrict__ w0, const float* __restrict__ b0,
                       const float* __restrict__ g0, const float* __restrict__ beta0,
                       const float* __restrict__ m0, const float* __restrict__ v0,
                       const float* __restrict__ wnw0, const float* __restrict__ wnb0,
                       const float* __restrict__ wng0, const float* __restrict__ wnbe0,
                       const float* __restrict__ wnm0, const float* __restrict__ wnv0,
                       const float* __restrict__ wnw1, const float* __restrict__ wnb1,
                       const float* __restrict__ wng1, const float* __restrict__ wnbe1,
                       const float* __restrict__ wnm1, const float* __restrict__ wnv1,
                       const float* __restrict__ wnw2, const float* __restrict__ wnb2,
                       const float* __restrict__ wng2, const float* __restrict__ wnbe2,
                       const float* __restrict__ wnm2, const float* __restrict__ wnv2,
                       const float* __restrict__ lw, const float* __restrict__ lb,
                       const float* __restrict__ lg, const float* __restrict__ lbeta,
                       const float* __restrict__ lm, const float* __restrict__ lv,
                       const float* __restrict__ x,
                       _Float16* __restrict__ x1L,
                       _Float16* __restrict__ whF,
                       float* __restrict__ lbf,
                       float* __restrict__ wnP,
                       int* __restrict__ cnt)
{
    const int tid = threadIdx.x;

    if (blockIdx.x >= 1152) {
        // ---------------- prep blocks ----------------
        int idx = (blockIdx.x - 1152) * 256 + tid;
        if (idx < 65536) {
            int j    = idx & 7;
            int lane = (idx >> 3) & 63;
            int kg   = (idx >> 9) & 63;   // kg16: 0..63 (K groups of 16)
            int nt   = idx >> 15;         // 0..1 (n-tile of 32)
            int k = kg * 16 + ((lane >> 5) & 1) * 8 + j;
            int n = nt * 32 + (lane & 31);
            float s = lg[n] * rsqrtf(lv[n] + EPSBN);
            whF[idx] = (_Float16)(lw[n * 1024 + k] * s);
        } else if (idx < 65600) {
            int j = idx - 65536;
            float s = lg[j] * rsqrtf(lv[j] + EPSBN);
            lbf[j] = (lb[j] - lm[j]) * s + lbeta[j];
        } else if (idx < 65848) {
            int t = idx - 65600;
            // wnP layout: [0,24) w0n  [24,32) b0n  [32,96) w1n  [96,104) b1n
            //             [104,232) w2n  [232,248) b2n   (all BN-fused)
            if (t < 24)       { int o = t / 3;           float s = wng0[o] * rsqrtf(wnv0[o] + EPSBN); wnP[t] = wnw0[t] * s; }
            else if (t < 32)  { int o = t - 24;          float s = wng0[o] * rsqrtf(wnv0[o] + EPSBN); wnP[t] = (wnb0[o] - wnm0[o]) * s + wnbe0[o]; }
            else if (t < 96)  { int t2 = t - 32;  int o = t2 >> 3; float s = wng1[o] * rsqrtf(wnv1[o] + EPSBN); wnP[t] = wnw1[t2] * s; }
            else if (t < 104) { int o = t - 96;          float s = wng1[o] * rsqrtf(wnv1[o] + EPSBN); wnP[t] = (wnb1[o] - wnm1[o]) * s + wnbe1[o]; }
            else if (t < 232) { int t2 = t - 104; int o = t2 >> 3; float s = wng2[o] * rsqrtf(wnv2[o] + EPSBN); wnP[t] = wnw2[t2] * s; }
            else if (t < 248) { int o = t - 232;         float s = wng2[o] * rsqrtf(wnv2[o] + EPSBN); wnP[t] = (wnb2[o] - wnm2[o]) * s + wnbe2[o]; }
        } else if (idx == 65848) {
            *cnt = 0;                     // work-steal counter for main kernel
        }
        return;
    }

    // ---------------- conv0 blocks ----------------
    __shared__ float wSt[16][64];   // [cin][cout], BN-folded locally
    __shared__ float bS[64];
    for (int t = tid; t < 1024; t += 256) {
        int o = t >> 4, ci = t & 15;
        float s = g0[o] * rsqrtf(v0[o] + EPSBN);
        wSt[ci][o] = w0[t] * s;
    }
    if (tid < 64) {
        float s = g0[tid] * rsqrtf(v0[tid] + EPSBN);
        bS[tid] = (b0[tid] - m0[tid]) * s + beta0[tid];
    }
    __syncthreads();

    // block owns 128 pixels; 128 never straddles a batch (HWPROD%128==0)
    const int pixb = blockIdx.x * 128;
    const int b  = pixb / HWPROD;
    const int pb = pixb - b * HWPROD;
    const int p4  = tid >> 3;      // pixel slot 0..31
    const int oct = tid & 7;       // co-octet 0..7

    float xv[4][16];
#pragma unroll
    for (int q = 0; q < 4; q++) {
        const int p = pb + q * 32 + p4;
#pragma unroll
        for (int cin = 0; cin < 16; cin++)
            xv[q][cin] = x[((size_t)b * 16 + cin) * HWPROD + p];
    }

    const f32x4* wSt4 = reinterpret_cast<const f32x4*>(wSt);   // [16][16] quads
    const f32x4* bS4  = reinterpret_cast<const f32x4*>(bS);

    f32x4 acc[4][2];
    {
        f32x4 ba = bS4[oct * 2], bb = bS4[oct * 2 + 1];
#pragma unroll
        for (int q = 0; q < 4; q++) { acc[q][0] = ba; acc[q][1] = bb; }
    }
#pragma unroll
    for (int cin = 0; cin < 16; cin++) {
        const f32x4 wa = wSt4[cin * 16 + oct * 2];
        const f32x4 wb = wSt4[cin * 16 + oct * 2 + 1];
#pragma unroll
        for (int q = 0; q < 4; q++) {
            const float xc = xv[q][cin];
            const f32x4 xb = { xc, xc, xc, xc };
            acc[q][0] = __builtin_elementwise_fma(xb, wa, acc[q][0]);
            acc[q][1] = __builtin_elementwise_fma(xb, wb, acc[q][1]);
        }
    }
    const f32x4 z4 = { 0.f, 0.f, 0.f, 0.f };
#pragma unroll
    for (int q = 0; q < 4; q++) {
        union { f16x4 h4[2]; f16x8 v; } O;
        O.h4[0] = __builtin_convertvector(__builtin_elementwise_max(acc[q][0], z4), f16x4);
        O.h4[1] = __builtin_convertvector(__builtin_elementwise_max(acc[q][1], z4), f16x4);
        *(f16x8*)(x1L + (size_t)(pixb + q * 32 + p4) * 64 + oct * 8) = O.v;
    }
}

// ---------------------------------------------------------------------------
// main fused kernel R17 = R15 strip body, wrapped in work-stealing persistent
// blocks. R16 diagnosis: 2304 blocks on 8-resident/CU => half the runtime is
// a 1-block-per-CU tail (occupancy algebra: T_tail ~= 0.96 T_main). Fix:
// grid 2048 (8/CU, exactly resident); blocks pop strip ids from a global
// atomic counter until 2304 strips are done -> makespan ~(9/8)T not 2T.
// Claim barrier doubles as the LDS-reuse fence between strips.
// ---------------------------------------------------------------------------
__global__ __launch_bounds__(128, 2) void pconv_main_k(const float* __restrict__ gxyz,
                                                       const _Float16* __restrict__ x1L,
                                                       const _Float16* __restrict__ whF,
                                                       const float* __restrict__ lbf,
                                                       const float* __restrict__ wnP,
                                                       int* cnt,
                                                       float* __restrict__ out)
{
    __shared__ __align__(16) char smem[19456];
    __shared__ int sW;
    unsigned*  xSu = reinterpret_cast<unsigned*>(smem);   // [32 cpair][4r*34c] dwords, stride 137
    _Float16*  gzF = reinterpret_cast<_Float16*>(smem);   // [64 px][152] halves (dead after S2)
    float*     Cb  = reinterpret_cast<float*>(smem);      // [64 n][67] f32 (epilogue)

    const int tid = threadIdx.x;
    const int lane = tid & 63;
    const int w    = tid >> 6;        // wave = row strip (h+w)
    const int p31  = lane & 31;       // pixel col within strip
    const int oh   = lane >> 5;       // o-half / k-octet
    const int pixb = w * 32 + p31;
    const f16x8* whF8 = (const f16x8*)whF;
    const unsigned* xrow = xSu + w * 34 + p31;

    while (true) {
        if (tid == 0) sW = atomicAdd(cnt, 1);
        __syncthreads();                  // B0: claim visible; prev strip done
        const int s = sW;
        if (s >= NSTRIP) break;

        // strip decode: s -> b(4) x hb(96) x c6(6)
        const int b   = s / (96 * 6);
        const int rem = s % (96 * 6);
        const int hb  = rem / 6;
        const int c6  = rem % 6;
        const int h   = hb * 2;
        const int wc0 = c6 * 32;

        // ---- WeightNet 3->8->8->16 (BN+ReLU fused): 576 (pixel,tap) units ----
        for (int u = tid; u < 576; u += 128) {
            int col = u & 31, rrow = (u >> 5) & 1, tap = u >> 6;
            size_t base = ((size_t)(b * 3) * 9 + tap) * HWPROD + (size_t)(h + rrow) * WW + wc0 + col;
            float z0 = gxyz[base];
            float z1 = gxyz[base + (size_t)9 * HWPROD];
            float z2 = gxyz[base + (size_t)18 * HWPROD];
            float h0[8], h1[8];
#pragma unroll
            for (int o = 0; o < 8; o++) {
                float a = wnP[24 + o] + wnP[o * 3 + 0] * z0 + wnP[o * 3 + 1] * z1 + wnP[o * 3 + 2] * z2;
                h0[o] = fmaxf(a, 0.f);
            }
#pragma unroll
            for (int o = 0; o < 8; o++) {
                float a = wnP[96 + o];
#pragma unroll
                for (int c = 0; c < 8; c++) a += wnP[32 + o * 8 + c] * h0[c];
                h1[o] = fmaxf(a, 0.f);
            }
            float g[16];
#pragma unroll
            for (int o = 0; o < 16; o++) {
                float a = wnP[232 + o];
#pragma unroll
                for (int c = 0; c < 8; c++) a += wnP[104 + o * 8 + c] * h1[c];
                g[o] = fmaxf(a, 0.f);
            }
            f16x8 lo, hi;
#pragma unroll
            for (int o = 0; o < 8; o++) { lo[o] = (_Float16)g[o]; hi[o] = (_Float16)g[o + 8]; }
            int px = u & 63;
            *(f16x8*)&gzF[px * 152 + tap * 16]     = lo;
            *(f16x8*)&gzF[px * 152 + tap * 16 + 8] = hi;
        }
        __syncthreads();   // S1: gzF visible

        // gz for this lane's (pixel, o-half): 9 taps x 4 f16x2 pairs in regs
        f16x2 gq2[9][4];
#pragma unroll
        for (int t = 0; t < 9; t++) {
            union { f16x8 v; f16x2 h[4]; } G;
            G.v = *(const f16x8*)&gzF[pixb * 152 + t * 16 + oh * 8];
#pragma unroll
            for (int d = 0; d < 4; d++) gq2[t][d] = G.h[d];
        }
        __syncthreads();   // S2: gzF dead; xS region may be written

        // ---- stage x1 halo transposed: xS[cpair][rr*34+cc] f16x2, stride 137 ----
        for (int i = 0; i < 16; i++) {
            int u  = i * 128 + tid;
            int cq = u & 15;                  // channel quad (4 ch = 2 pairs)
            int cc = ((u >> 4) & 31) + 1;
            int rr = u >> 9;                  // 0..3
            int hr = h + rr - 1;
            uint2 v = {0u, 0u};
            if (hr >= 0 && hr < HH)
                v = *(const uint2*)(x1L + (((size_t)b * HH + hr) * WW + wc0 + cc - 1) * 64 + cq * 4);
            xSu[(2 * cq) * 137 + rr * 34 + cc]     = v.x;
            xSu[(2 * cq + 1) * 137 + rr * 34 + cc] = v.y;
        }
        {
            int cq   = tid & 15;
            int side = (tid >> 4) & 1;
            int rr   = tid >> 5;              // 0..3
            int cc   = side ? 33 : 0;
            int hr = h + rr - 1;
            int wc = wc0 + cc - 1;
            uint2 v = {0u, 0u};
            if (hr >= 0 && hr < HH && wc >= 0 && wc < WW)
                v = *(const uint2*)(x1L + (((size_t)b * HH + hr) * WW + wc) * 64 + cq * 4);
            xSu[(2 * cq) * 137 + rr * 34 + cc]     = v.x;
            xSu[(2 * cq + 1) * 137 + rr * 34 + cc] = v.y;
        }
        __syncthreads();   // S3: xS ready

        // ---- main loop: 32 channel-pair chunks, zero barriers ----
        f32x16 facc0, facc1;
#pragma unroll
        for (int r = 0; r < 16; r++) { facc0[r] = 0.f; facc1[r] = 0.f; }

#pragma unroll 2
        for (int cb = 0; cb < 32; cb++) {
            const int c0 = 2 * cb, c1 = 2 * cb + 1;
            const f16x8 wh00 = whF8[(0 * 64 + c0) * 64 + lane];
            const f16x8 wh01 = whF8[(1 * 64 + c0) * 64 + lane];
            const f16x8 wh10 = whF8[(0 * 64 + c1) * 64 + lane];
            const f16x8 wh11 = whF8[(1 * 64 + c1) * 64 + lane];

            union { f16x2 h2[4]; f16x8 v; } av0, av1;
#pragma unroll
            for (int d = 0; d < 4; d++) { av0.h2[d] = f16x2{0, 0}; av1.h2[d] = f16x2{0, 0}; }
            const unsigned* xr = xrow + cb * 137;
#pragma unroll
            for (int ky = 0; ky < 3; ky++) {
#pragma unroll
                for (int kx = 0; kx < 3; kx++) {
                    const int t = ky * 3 + kx;
                    f16x2 xq;
                    { unsigned tmp = xr[ky * 34 + kx]; xq = *(f16x2*)&tmp; }
#pragma unroll
                    for (int d = 0; d < 4; d++) {
                        // av0 += broadcast(xq.lo) * gq2   (even channel = lo)
                        asm("v_pk_fma_f16 %0, %1, %2, %0 op_sel:[0,0,0] op_sel_hi:[0,1,1]"
                            : "+v"(av0.h2[d]) : "v"(xq), "v"(gq2[t][d]));
                        // av1 += broadcast(xq.hi) * gq2   (odd channel = hi)
                        asm("v_pk_fma_f16 %0, %1, %2, %0 op_sel:[1,0,0] op_sel_hi:[1,1,1]"
                            : "+v"(av1.h2[d]) : "v"(xq), "v"(gq2[t][d]));
                    }
                }
            }
            facc0 = __builtin_amdgcn_mfma_f32_32x32x16_f16(av0.v, wh00, facc0, 0, 0, 0);
            facc1 = __builtin_amdgcn_mfma_f32_32x32x16_f16(av0.v, wh01, facc1, 0, 0, 0);
            facc0 = __builtin_amdgcn_mfma_f32_32x32x16_f16(av1.v, wh10, facc0, 0, 0, 0);
            facc1 = __builtin_amdgcn_mfma_f32_32x32x16_f16(av1.v, wh11, facc1, 0, 0, 0);
        }
        __syncthreads();   // S4: xS dead (all waves done with MFMAs)

        // ---- epilogue: C/D col=lane&31 (=n), row m=(r&3)+8*(r>>2)+4*oh ----
        {
            const int n0 = p31;
            const float bias0 = lbf[n0];
            const float bias1 = lbf[n0 + 32];
#pragma unroll
            for (int r = 0; r < 16; r++) {
                const int m = (r & 3) + 8 * (r >> 2) + 4 * oh;   // pixel col
                Cb[n0 * 67 + w * 32 + m]        = fmaxf(facc0[r] + bias0, 0.f);
                Cb[(n0 + 32) * 67 + w * 32 + m] = fmaxf(facc1[r] + bias1, 0.f);
            }
        }
        __syncthreads();   // S5
        {
            const int col = tid & 31;
            const int nq  = tid >> 5;   // 0..3 -> 16 n's each
#pragma unroll
            for (int rr = 0; rr < 2; rr++) {
                size_t ob = ((size_t)b * 64 + nq * 16) * HWPROD + (size_t)(h + rr) * WW + wc0 + col;
#pragma unroll
                for (int i = 0; i < 16; i++)
                    out[ob + (size_t)i * HWPROD] = Cb[(nq * 16 + i) * 67 + rr * 32 + col];
            }
        }
        // next-iteration claim barrier (B0) fences Cb reads vs gzF writes
    }
}

// ---------------------------------------------------------------------------
extern "C" void kernel_launch(void* const* d_in, const int* in_sizes, int n_in,
                              void* d_out, int out_size, void* d_ws, size_t ws_size,
                              hipStream_t stream) {
    const float* x    = (const float*)d_in[0];
    // d_in[1] = group_mask: unused by the reference
    const float* gxyz = (const float*)d_in[2];

    char* ws = (char*)d_ws;
    _Float16* x1L = (_Float16*)ws;                        // 9,437,184 halves (18.9 MB)
    _Float16* whF = x1L + 9437184;                        // 65,536 halves
    float* lbf = (float*)(whF + 65536);                   // 64
    float* wnP = lbf + 64;                                // 248
    int* cnt = (int*)(wnP + 248);                         // work-steal counter

    prep_conv0_k<<<1414, 256, 0, stream>>>(
        (const float*)d_in[3],  (const float*)d_in[4],  (const float*)d_in[5],
        (const float*)d_in[6],  (const float*)d_in[7],  (const float*)d_in[8],
        (const float*)d_in[9],  (const float*)d_in[10], (const float*)d_in[11],
        (const float*)d_in[12], (const float*)d_in[13], (const float*)d_in[14],
        (const float*)d_in[15], (const float*)d_in[16], (const float*)d_in[17],
        (const float*)d_in[18], (const float*)d_in[19], (const float*)d_in[20],
        (const float*)d_in[21], (const float*)d_in[22], (const float*)d_in[23],
        (const float*)d_in[24], (const float*)d_in[25], (const float*)d_in[26],
        (const float*)d_in[27], (const float*)d_in[28], (const float*)d_in[29],
        (const float*)d_in[30], (const float*)d_in[31], (const float*)d_in[32],
        x, x1L, whF, lbf, wnP, cnt);

    pconv_main_k<<<2048, 128, 0, stream>>>(gxyz, x1L, whF, lbf, wnP, cnt,
                                           (float*)d_out);
}

// Round 8
// 230.353 us; speedup vs baseline: 1.0224x; 1.0224x over previous
//
#include <hip/hip_runtime.h>
#include <hip/hip_bf16.h>

#define HH 192
#define WW 192
#define HWPROD (192*192)
#define EPSBN 1e-5f

typedef _Float16 f16x8 __attribute__((ext_vector_type(8)));
typedef _Float16 f16x4 __attribute__((ext_vector_type(4)));
typedef _Float16 f16x2 __attribute__((ext_vector_type(2)));
typedef float f32x4 __attribute__((ext_vector_type(4)));
typedef float f32x16 __attribute__((ext_vector_type(16)));

// ---------------------------------------------------------------------------
// prep_conv0 (R16 version: conv0 with coalesced f16x8 stores; whF prep with
// the proven 32x32x16 B-operand mapping).
// ---------------------------------------------------------------------------
__global__ __launch_bounds__(256) void prep_conv0_k(
                       const float* __restrict__ w0, const float* __restrict__ b0,
                       const float* __restrict__ g0, const float* __restrict__ beta0,
                       const float* __restrict__ m0, const float* __restrict__ v0,
                       const float* __restrict__ wnw0, const float* __restrict__ wnb0,
                       const float* __restrict__ wng0, const float* __restrict__ wnbe0,
                       const float* __restrict__ wnm0, const float* __restrict__ wnv0,
                       const float* __restrict__ wnw1, const float* __restrict__ wnb1,
                       const float* __restrict__ wng1, const float* __restrict__ wnbe1,
                       const float* __restrict__ wnm1, const float* __restrict__ wnv1,
                       const float* __restrict__ wnw2, const float* __restrict__ wnb2,
                       const float* __restrict__ wng2, const float* __restrict__ wnbe2,
                       const float* __restrict__ wnm2, const float* __restrict__ wnv2,
                       const float* __restrict__ lw, const float* __restrict__ lb,
                       const float* __restrict__ lg, const float* __restrict__ lbeta,
                       const float* __restrict__ lm, const float* __restrict__ lv,
                       const float* __restrict__ x,
                       _Float16* __restrict__ x1L,
                       _Float16* __restrict__ whF,
                       float* __restrict__ lbf,
                       float* __restrict__ wnP)
{
    const int tid = threadIdx.x;

    if (blockIdx.x >= 1152) {
        // ---------------- prep blocks ----------------
        int idx = (blockIdx.x - 1152) * 256 + tid;
        if (idx < 65536) {
            int j    = idx & 7;
            int lane = (idx >> 3) & 63;
            int kg   = (idx >> 9) & 63;   // kg16: 0..63 (K groups of 16)
            int nt   = idx >> 15;         // 0..1 (n-tile of 32)
            int k = kg * 16 + ((lane >> 5) & 1) * 8 + j;
            int n = nt * 32 + (lane & 31);
            float s = lg[n] * rsqrtf(lv[n] + EPSBN);
            whF[idx] = (_Float16)(lw[n * 1024 + k] * s);
        } else if (idx < 65600) {
            int j = idx - 65536;
            float s = lg[j] * rsqrtf(lv[j] + EPSBN);
            lbf[j] = (lb[j] - lm[j]) * s + lbeta[j];
        } else if (idx < 65848) {
            int t = idx - 65600;
            // wnP layout: [0,24) w0n  [24,32) b0n  [32,96) w1n  [96,104) b1n
            //             [104,232) w2n  [232,248) b2n   (all BN-fused)
            if (t < 24)       { int o = t / 3;           float s = wng0[o] * rsqrtf(wnv0[o] + EPSBN); wnP[t] = wnw0[t] * s; }
            else if (t < 32)  { int o = t - 24;          float s = wng0[o] * rsqrtf(wnv0[o] + EPSBN); wnP[t] = (wnb0[o] - wnm0[o]) * s + wnbe0[o]; }
            else if (t < 96)  { int t2 = t - 32;  int o = t2 >> 3; float s = wng1[o] * rsqrtf(wnv1[o] + EPSBN); wnP[t] = wnw1[t2] * s; }
            else if (t < 104) { int o = t - 96;          float s = wng1[o] * rsqrtf(wnv1[o] + EPSBN); wnP[t] = (wnb1[o] - wnm1[o]) * s + wnbe1[o]; }
            else if (t < 232) { int t2 = t - 104; int o = t2 >> 3; float s = wng2[o] * rsqrtf(wnv2[o] + EPSBN); wnP[t] = wnw2[t2] * s; }
            else if (t < 248) { int o = t - 232;         float s = wng2[o] * rsqrtf(wnv2[o] + EPSBN); wnP[t] = (wnb2[o] - wnm2[o]) * s + wnbe2[o]; }
        }
        return;
    }

    // ---------------- conv0 blocks ----------------
    __shared__ float wSt[16][64];   // [cin][cout], BN-folded locally
    __shared__ float bS[64];
    for (int t = tid; t < 1024; t += 256) {
        int o = t >> 4, ci = t & 15;
        float s = g0[o] * rsqrtf(v0[o] + EPSBN);
        wSt[ci][o] = w0[t] * s;
    }
    if (tid < 64) {
        float s = g0[tid] * rsqrtf(v0[tid] + EPSBN);
        bS[tid] = (b0[tid] - m0[tid]) * s + beta0[tid];
    }
    __syncthreads();

    // block owns 128 pixels; 128 never straddles a batch (HWPROD%128==0)
    const int pixb = blockIdx.x * 128;
    const int b  = pixb / HWPROD;
    const int pb = pixb - b * HWPROD;
    const int p4  = tid >> 3;      // pixel slot 0..31
    const int oct = tid & 7;       // co-octet 0..7

    float xv[4][16];
#pragma unroll
    for (int q = 0; q < 4; q++) {
        const int p = pb + q * 32 + p4;
#pragma unroll
        for (int cin = 0; cin < 16; cin++)
            xv[q][cin] = x[((size_t)b * 16 + cin) * HWPROD + p];
    }

    const f32x4* wSt4 = reinterpret_cast<const f32x4*>(wSt);   // [16][16] quads
    const f32x4* bS4  = reinterpret_cast<const f32x4*>(bS);

    f32x4 acc[4][2];
    {
        f32x4 ba = bS4[oct * 2], bb = bS4[oct * 2 + 1];
#pragma unroll
        for (int q = 0; q < 4; q++) { acc[q][0] = ba; acc[q][1] = bb; }
    }
#pragma unroll
    for (int cin = 0; cin < 16; cin++) {
        const f32x4 wa = wSt4[cin * 16 + oct * 2];
        const f32x4 wb = wSt4[cin * 16 + oct * 2 + 1];
#pragma unroll
        for (int q = 0; q < 4; q++) {
            const float xc = xv[q][cin];
            const f32x4 xb = { xc, xc, xc, xc };
            acc[q][0] = __builtin_elementwise_fma(xb, wa, acc[q][0]);
            acc[q][1] = __builtin_elementwise_fma(xb, wb, acc[q][1]);
        }
    }
    const f32x4 z4 = { 0.f, 0.f, 0.f, 0.f };
#pragma unroll
    for (int q = 0; q < 4; q++) {
        union { f16x4 h4[2]; f16x8 v; } O;
        O.h4[0] = __builtin_convertvector(__builtin_elementwise_max(acc[q][0], z4), f16x4);
        O.h4[1] = __builtin_convertvector(__builtin_elementwise_max(acc[q][1], z4), f16x4);
        *(f16x8*)(x1L + (size_t)(pixb + q * 32 + p4) * 64 + oct * 8) = O.v;
    }
}

// ---------------------------------------------------------------------------
// main fused kernel R18: R15 strip body with LDS cut 19.5 KB -> 8.8 KB.
//  Diagnosis (R17): residency capped at ~4.5 blocks/CU by an effective LDS
//  pool of ~96 KB (every round fits blocks x LDS ~= 90-100 KB); kernel is
//  latency-bound (no pipe > 25% saturated). Shrink LDS to double residency:
//   - WeightNet per-lane in registers (kills the 19.4 KB gzF; lane (p31,oh)
//     computes its own pixel's 3->8->8 layers (2x dup) + its 8-wide half of
//     layer 2; identical expressions -> bit-identical gq2),
//   - channel-split staging: 16 cpairs at a time (8768 B),
//   - two-pass epilogue: Cb [32 n][65] f32 (8320 B) per n-tile.
//  Grid back to 2304 (work-stealing reverted). Proven layouts unchanged:
//  whF B-operand, A-fragment direct build, C/D epilogue mapping.
// ---------------------------------------------------------------------------
__global__ __launch_bounds__(128, 2) void pconv_main_k(const float* __restrict__ gxyz,
                                                       const _Float16* __restrict__ x1L,
                                                       const _Float16* __restrict__ whF,
                                                       const float* __restrict__ lbf,
                                                       const float* __restrict__ wnP,
                                                       float* __restrict__ out)
{
    __shared__ __align__(16) char smem[8768];
    unsigned*  xSu = reinterpret_cast<unsigned*>(smem);   // [16 cpair][137] dwords = 8768 B
    float*     Cb  = reinterpret_cast<float*>(smem);      // [32 n][65] f32 = 8320 B (aliases xSu)

    const int tid = threadIdx.x;
    const int bid = blockIdx.x;
    // grid: b(4) x hb(96) x c6(6)
    const int b   = bid / (96 * 6);
    const int rem = bid % (96 * 6);
    const int hb  = rem / 6;
    const int c6  = rem % 6;
    const int h   = hb * 2;
    const int wc0 = c6 * 32;

    const int lane = tid & 63;
    const int w    = tid >> 6;        // wave = row strip (h+w)
    const int p31  = lane & 31;       // pixel col within strip
    const int oh   = lane >> 5;       // o-half / k-octet

    // ---- stage x1 halo HALF 0 (channels 0..31 = cpairs 0..15), stride 137 --
    auto stageHalf = [&](int hf) {
#pragma unroll
        for (int i = 0; i < 8; i++) {
            int u   = i * 128 + tid;
            int cqL = u & 7;                  // local channel quad (2 cpairs)
            int cc  = ((u >> 3) & 31) + 1;    // interior cols 1..32
            int rr  = u >> 8;                 // 0..3
            int hr = h + rr - 1;
            uint2 v = {0u, 0u};
            if (hr >= 0 && hr < HH)
                v = *(const uint2*)(x1L + (((size_t)b * HH + hr) * WW + wc0 + cc - 1) * 64 + (hf * 8 + cqL) * 4);
            xSu[(2 * cqL) * 137 + rr * 34 + cc]     = v.x;
            xSu[(2 * cqL + 1) * 137 + rr * 34 + cc] = v.y;
        }
        if (tid < 64) {
            int cqL  = tid & 7;
            int side = (tid >> 3) & 1;
            int rr   = tid >> 4;              // 0..3
            int cc   = side ? 33 : 0;
            int hr = h + rr - 1;
            int wc = wc0 + cc - 1;
            uint2 v = {0u, 0u};
            if (hr >= 0 && hr < HH && wc >= 0 && wc < WW)
                v = *(const uint2*)(x1L + (((size_t)b * HH + hr) * WW + wc) * 64 + (hf * 8 + cqL) * 4);
            xSu[(2 * cqL) * 137 + rr * 34 + cc]     = v.x;
            xSu[(2 * cqL + 1) * 137 + rr * 34 + cc] = v.y;
        }
    };

    stageHalf(0);

    // ---- WeightNet per-lane, in registers (no LDS, no barriers) ----
    // lane computes gz for its own pixel (row h+w, col wc0+p31) and o-half oh.
    f16x2 gq2[9][4];
#pragma unroll
    for (int tap = 0; tap < 9; tap++) {
        size_t base = ((size_t)(b * 3) * 9 + tap) * HWPROD + (size_t)(h + w) * WW + wc0 + p31;
        float z0 = gxyz[base];
        float z1 = gxyz[base + (size_t)9 * HWPROD];
        float z2 = gxyz[base + (size_t)18 * HWPROD];
        float h0[8], h1[8];
#pragma unroll
        for (int o = 0; o < 8; o++) {
            float a = wnP[24 + o] + wnP[o * 3 + 0] * z0 + wnP[o * 3 + 1] * z1 + wnP[o * 3 + 2] * z2;
            h0[o] = fmaxf(a, 0.f);
        }
#pragma unroll
        for (int o = 0; o < 8; o++) {
            float a = wnP[96 + o];
#pragma unroll
            for (int c = 0; c < 8; c++) a += wnP[32 + o * 8 + c] * h0[c];
            h1[o] = fmaxf(a, 0.f);
        }
        float g[8];
#pragma unroll
        for (int j = 0; j < 8; j++) {
            const int o = oh * 8 + j;
            float a = wnP[232 + o];
#pragma unroll
            for (int c = 0; c < 8; c++) a += wnP[104 + o * 8 + c] * h1[c];
            g[j] = fmaxf(a, 0.f);
        }
#pragma unroll
        for (int d = 0; d < 4; d++)
            gq2[tap][d] = f16x2{ (_Float16)g[2 * d], (_Float16)g[2 * d + 1] };
    }
    __syncthreads();   // S1: xS half0 ready

    // ---- main loop: 2 channel-halves x 16 cpair chunks ----
    const f16x8* whF8 = (const f16x8*)whF;
    const unsigned* xrow = xSu + w * 34 + p31;

    f32x16 facc0, facc1;
#pragma unroll
    for (int r = 0; r < 16; r++) { facc0[r] = 0.f; facc1[r] = 0.f; }

#pragma unroll 1
    for (int hf = 0; hf < 2; hf++) {
#pragma unroll 2
        for (int cl = 0; cl < 16; cl++) {
            const int c0 = 2 * (hf * 16 + cl), c1 = c0 + 1;
            const f16x8 wh00 = whF8[(0 * 64 + c0) * 64 + lane];
            const f16x8 wh01 = whF8[(1 * 64 + c0) * 64 + lane];
            const f16x8 wh10 = whF8[(0 * 64 + c1) * 64 + lane];
            const f16x8 wh11 = whF8[(1 * 64 + c1) * 64 + lane];

            union { f16x2 h2[4]; f16x8 v; } av0, av1;
#pragma unroll
            for (int d = 0; d < 4; d++) { av0.h2[d] = f16x2{0, 0}; av1.h2[d] = f16x2{0, 0}; }
            const unsigned* xr = xrow + cl * 137;
#pragma unroll
            for (int ky = 0; ky < 3; ky++) {
#pragma unroll
                for (int kx = 0; kx < 3; kx++) {
                    const int t = ky * 3 + kx;
                    f16x2 xq;
                    { unsigned tmp = xr[ky * 34 + kx]; xq = *(f16x2*)&tmp; }
#pragma unroll
                    for (int d = 0; d < 4; d++) {
                        // av0 += broadcast(xq.lo) * gq2   (even channel = lo)
                        asm("v_pk_fma_f16 %0, %1, %2, %0 op_sel:[0,0,0] op_sel_hi:[0,1,1]"
                            : "+v"(av0.h2[d]) : "v"(xq), "v"(gq2[t][d]));
                        // av1 += broadcast(xq.hi) * gq2   (odd channel = hi)
                        asm("v_pk_fma_f16 %0, %1, %2, %0 op_sel:[1,0,0] op_sel_hi:[1,1,1]"
                            : "+v"(av1.h2[d]) : "v"(xq), "v"(gq2[t][d]));
                    }
                }
            }
            facc0 = __builtin_amdgcn_mfma_f32_32x32x16_f16(av0.v, wh00, facc0, 0, 0, 0);
            facc1 = __builtin_amdgcn_mfma_f32_32x32x16_f16(av0.v, wh01, facc1, 0, 0, 0);
            facc0 = __builtin_amdgcn_mfma_f32_32x32x16_f16(av1.v, wh10, facc0, 0, 0, 0);
            facc1 = __builtin_amdgcn_mfma_f32_32x32x16_f16(av1.v, wh11, facc1, 0, 0, 0);
        }
        __syncthreads();   // S2/S4: this half's xS consumed
        if (hf == 0) {
            stageHalf(1);
            __syncthreads();   // S3: xS half1 ready
        }
    }

    // ---- two-pass epilogue: C/D col=lane&31 (=n), row m=(r&3)+8*(r>>2)+4*oh
#pragma unroll 1
    for (int pass = 0; pass < 2; pass++) {
        const f32x16& fa = pass ? facc1 : facc0;
        {
            const float bias = lbf[pass * 32 + p31];
#pragma unroll
            for (int r = 0; r < 16; r++) {
                const int m = (r & 3) + 8 * (r >> 2) + 4 * oh;   // pixel col
                Cb[p31 * 65 + w * 32 + m] = fmaxf(fa[r] + bias, 0.f);
            }
        }
        __syncthreads();   // Cb(pass) visible
        {
            const int col = tid & 31;
            const int nh  = tid >> 5;   // 0..3 -> 8 n's each
#pragma unroll
            for (int rr = 0; rr < 2; rr++) {
                size_t ob = ((size_t)b * 64 + pass * 32 + nh * 8) * HWPROD + (size_t)(h + rr) * WW + wc0 + col;
#pragma unroll
                for (int i = 0; i < 8; i++)
                    out[ob + (size_t)i * HWPROD] = Cb[(nh * 8 + i) * 65 + rr * 32 + col];
            }
        }
        if (pass == 0) __syncthreads();   // Cb consumed before overwrite
    }
}

// ---------------------------------------------------------------------------
extern "C" void kernel_launch(void* const* d_in, const int* in_sizes, int n_in,
                              void* d_out, int out_size, void* d_ws, size_t ws_size,
                              hipStream_t stream) {
    const float* x    = (const float*)d_in[0];
    // d_in[1] = group_mask: unused by the reference
    const float* gxyz = (const float*)d_in[2];

    char* ws = (char*)d_ws;
    _Float16* x1L = (_Float16*)ws;                        // 9,437,184 halves (18.9 MB)
    _Float16* whF = x1L + 9437184;                        // 65,536 halves
    float* lbf = (float*)(whF + 65536);                   // 64
    float* wnP = lbf + 64;                                // 248

    prep_conv0_k<<<1414, 256, 0, stream>>>(
        (const float*)d_in[3],  (const float*)d_in[4],  (const float*)d_in[5],
        (const float*)d_in[6],  (const float*)d_in[7],  (const float*)d_in[8],
        (const float*)d_in[9],  (const float*)d_in[10], (const float*)d_in[11],
        (const float*)d_in[12], (const float*)d_in[13], (const float*)d_in[14],
        (const float*)d_in[15], (const float*)d_in[16], (const float*)d_in[17],
        (const float*)d_in[18], (const float*)d_in[19], (const float*)d_in[20],
        (const float*)d_in[21], (const float*)d_in[22], (const float*)d_in[23],
        (const float*)d_in[24], (const float*)d_in[25], (const float*)d_in[26],
        (const float*)d_in[27], (const float*)d_in[28], (const float*)d_in[29],
        (const float*)d_in[30], (const float*)d_in[31], (const float*)d_in[32],
        x, x1L, whF, lbf, wnP);

    pconv_main_k<<<4 * 96 * 6, 128, 0, stream>>>(gxyz, x1L, whF, lbf, wnP,
                                                 (float*)d_out);
}